// Round 1
// baseline (302.710 us; speedup 1.0000x reference)
//
#include <hip/hip_runtime.h>
#include <hip/hip_bf16.h>
#include <math.h>

#define B_ 64
#define L_ 512
#define D_ 768
#define J_ 31
#define S_ 32
#define H_ 100
#define G3 300
#define NC_ 10
#define EMB_ 50

__device__ __forceinline__ float sigmoidf_(float x) { return 1.0f / (1.0f + expf(-x)); }
__device__ __forceinline__ float dot4_(float4 a, float4 b) {
    return a.x * b.x + a.y * b.y + a.z * b.z + a.w * b.w;
}

// ---------------------------------------------------------------------------
// K1: per-clause softmax-weighted pooling.  One block per (s, b).
// doc layout: [S][B][D]  (scan order)
// ---------------------------------------------------------------------------
#define TCAP 18
__global__ __launch_bounds__(256) void pool_kernel(
    const float* __restrict__ hs, const int* __restrict__ cb,
    const float* __restrict__ fc5w, const float* __restrict__ fc5b,
    float* __restrict__ doc)
{
    __shared__ __align__(16) float tile[TCAP * D_];
    __shared__ float sc_s[L_];
    __shared__ float red[8];

    int s = blockIdx.x, b = blockIdx.y;
    int start = (s == 0) ? 0 : cb[b * J_ + s - 1];
    int end   = (s == J_) ? L_ : cb[b * J_ + s];
    int nt = end - start;
    int tid = threadIdx.x;

    if (nt <= 0) {  // empty segment: ref would be NaN; never happens in setup
        for (int d = tid; d < D_; d += 256) doc[((size_t)s * B_ + b) * D_ + d] = 0.f;
        return;
    }
    bool staged = (nt <= TCAP);
    const float* base = hs + ((size_t)b * L_ + start) * D_;

    if (staged) {
        const float4* b4 = (const float4*)base;
        float4* t4 = (float4*)tile;
        int n4 = nt * (D_ / 4);
        for (int i = tid; i < n4; i += 256) t4[i] = b4[i];
    }
    int lane = tid & 63, wv = tid >> 6;
    float fw[12];
#pragma unroll
    for (int i = 0; i < 12; ++i) fw[i] = fc5w[i * 64 + lane];
    __syncthreads();

    // scores: one token per wave round-robin
    for (int t = wv; t < nt; t += 4) {
        const float* row = staged ? &tile[t * D_] : (base + (size_t)t * D_);
        float p = 0.f;
#pragma unroll
        for (int i = 0; i < 12; ++i) p += row[i * 64 + lane] * fw[i];
        for (int off = 32; off; off >>= 1) p += __shfl_xor(p, off);
        if (lane == 0) sc_s[t] = p + fc5b[0];
    }
    __syncthreads();

    // softmax over sc_s[0..nt)
    float lm = -INFINITY;
    for (int i = tid; i < nt; i += 256) lm = fmaxf(lm, sc_s[i]);
    for (int off = 32; off; off >>= 1) lm = fmaxf(lm, __shfl_xor(lm, off));
    if (lane == 0) red[wv] = lm;
    __syncthreads();
    float mx = fmaxf(fmaxf(red[0], red[1]), fmaxf(red[2], red[3]));
    float ls = 0.f;
    for (int i = tid; i < nt; i += 256) {
        float e = expf(sc_s[i] - mx);
        sc_s[i] = e;
        ls += e;
    }
    for (int off = 32; off; off >>= 1) ls += __shfl_xor(ls, off);
    if (lane == 0) red[4 + wv] = ls;
    __syncthreads();
    float inv = 1.f / (red[4] + red[5] + red[6] + red[7]);

    // weighted sum: thread owns dims tid, tid+256, tid+512
    float acc0 = 0.f, acc1 = 0.f, acc2 = 0.f;
    for (int t = 0; t < nt; ++t) {
        float w = sc_s[t] * inv;
        const float* row = staged ? &tile[t * D_] : (base + (size_t)t * D_);
        acc0 += w * row[tid];
        acc1 += w * row[256 + tid];
        acc2 += w * row[512 + tid];
    }
    float* o = doc + ((size_t)s * B_ + b) * D_;
    o[tid] = acc0; o[256 + tid] = acc1; o[512 + tid] = acc2;
}

// ---------------------------------------------------------------------------
// K2: gi = doc @ [Wf;Wb].T + [bf;bb]   M=2048, N=600, K=768  (64x64 tiles)
// ---------------------------------------------------------------------------
__global__ __launch_bounds__(256) void gemm_enc(
    const float* __restrict__ A,
    const float* __restrict__ Wf, const float* __restrict__ Wb,
    const float* __restrict__ bf_, const float* __restrict__ bb_,
    float* __restrict__ C)
{
    __shared__ __align__(16) float As[16][68];
    __shared__ __align__(16) float Ws[16][68];
    int n0 = blockIdx.x * 64, m0 = blockIdx.y * 64;
    int tid = threadIdx.x;
    int tx = tid & 15, ty = tid >> 4;
    int lr = tid >> 2, lk4 = tid & 3;
    float acc[4][4] = {};

    for (int kk = 0; kk < D_; kk += 16) {
        float4 av = *(const float4*)(A + ((size_t)(m0 + lr)) * D_ + kk + lk4 * 4);
        As[lk4 * 4 + 0][lr] = av.x; As[lk4 * 4 + 1][lr] = av.y;
        As[lk4 * 4 + 2][lr] = av.z; As[lk4 * 4 + 3][lr] = av.w;
        int n = n0 + lr;
        float4 wvv = make_float4(0.f, 0.f, 0.f, 0.f);
        if (n < G3)      wvv = *(const float4*)(Wf + (size_t)n * D_ + kk + lk4 * 4);
        else if (n < 600) wvv = *(const float4*)(Wb + (size_t)(n - G3) * D_ + kk + lk4 * 4);
        Ws[lk4 * 4 + 0][lr] = wvv.x; Ws[lk4 * 4 + 1][lr] = wvv.y;
        Ws[lk4 * 4 + 2][lr] = wvv.z; Ws[lk4 * 4 + 3][lr] = wvv.w;
        __syncthreads();
#pragma unroll
        for (int k = 0; k < 16; ++k) {
            float4 a4 = *(const float4*)&As[k][ty * 4];
            float4 w4 = *(const float4*)&Ws[k][tx * 4];
            float ai[4] = {a4.x, a4.y, a4.z, a4.w};
            float wj[4] = {w4.x, w4.y, w4.z, w4.w};
#pragma unroll
            for (int i = 0; i < 4; ++i)
#pragma unroll
                for (int j = 0; j < 4; ++j) acc[i][j] += ai[i] * wj[j];
        }
        __syncthreads();
    }
#pragma unroll
    for (int j = 0; j < 4; ++j) {
        int n = n0 + tx * 4 + j;
        if (n >= 600) continue;
        float bias = (n < G3) ? bf_[n] : bb_[n - G3];
#pragma unroll
        for (int i = 0; i < 4; ++i) {
            int m = m0 + ty * 4 + i;
            C[(size_t)m * 600 + n] = acc[i][j] + bias;
        }
    }
}

// ---------------------------------------------------------------------------
// K3: encoder scans.  128 blocks: bid<64 fwd batch, bid>=64 bwd batch.
// Whh rows live in registers (100 VGPR / thread).
// ---------------------------------------------------------------------------
__global__ __launch_bounds__(320) void enc_scan(
    const float* __restrict__ gi,
    const float* __restrict__ whh_f, const float* __restrict__ whh_b,
    const float* __restrict__ bhh_f, const float* __restrict__ bhh_b,
    float* __restrict__ out1, float* __restrict__ hT)
{
    __shared__ __align__(16) float h_s[H_];
    __shared__ float gh_s[G3];
    int bid = blockIdx.x;
    int b = bid & 63;
    bool bwd = (bid >= 64);
    const float* whh = bwd ? whh_b : whh_f;
    const float* bhh = bwd ? bhh_b : bhh_f;
    int j = threadIdx.x;

    float4 wrow[25];
    float bh = 0.f;
    if (j < G3) {
        const float4* wr = (const float4*)(whh + (size_t)j * H_);
#pragma unroll
        for (int q = 0; q < 25; ++q) wrow[q] = wr[q];
        bh = bhh[j];
    }
    if (j < H_) h_s[j] = 0.f;
    __syncthreads();

    for (int step = 0; step < S_; ++step) {
        int t = bwd ? (S_ - 1 - step) : step;
        if (j < G3) {
            const float4* h4 = (const float4*)h_s;
            float a[4] = {0.f, 0.f, 0.f, 0.f};
#pragma unroll
            for (int q = 0; q < 25; ++q) a[q & 3] += dot4_(wrow[q], h4[q]);
            gh_s[j] = bh + (a[0] + a[1]) + (a[2] + a[3]);
        }
        __syncthreads();
        if (j < H_) {
            const float* g = gi + ((size_t)t * B_ + b) * 600 + (bwd ? G3 : 0);
            float r = sigmoidf_(g[j]          + gh_s[j]);
            float z = sigmoidf_(g[H_ + j]     + gh_s[H_ + j]);
            float n = tanhf(    g[2 * H_ + j] + r * gh_s[2 * H_ + j]);
            float hn = (1.f - z) * n + z * h_s[j];
            h_s[j] = hn;
            out1[((size_t)t * B_ + b) * 200 + (bwd ? H_ : 0) + j] = hn;
        }
        __syncthreads();
    }
    if (!bwd && j < H_) hT[b * H_ + j] = h_s[j];
}

// ---------------------------------------------------------------------------
// K4: generic small NT GEMM: C[m][n] = sum_k A[m][k]*W[n][woff+k] (+bias[n])
// ---------------------------------------------------------------------------
__global__ void small_gemm(
    const float* __restrict__ A, int lda, int K,
    const float* __restrict__ W, int wstride, int woff,
    const float* __restrict__ bias,
    float* __restrict__ C, int N, int ldc,
    int BM, int nChunk)
{
    extern __shared__ float sm[];
    int Kp = K + 1;
    float* Wl = sm;
    float* Al = sm + (size_t)nChunk * Kp;
    int nBase = blockIdx.x * nChunk;
    int nCnt = min(nChunk, N - nBase);
    int m0 = blockIdx.y * BM;

    for (int i = threadIdx.x; i < nCnt * K; i += blockDim.x) {
        int n = i / K, k = i - n * K;
        Wl[n * Kp + k] = W[(size_t)(nBase + n) * wstride + woff + k];
    }
    for (int i = threadIdx.x; i < BM * K; i += blockDim.x) {
        int mi = i / K, k = i - mi * K;
        Al[mi * Kp + k] = A[(size_t)(m0 + mi) * lda + k];
    }
    __syncthreads();

    for (int o = threadIdx.x; o < BM * nCnt; o += blockDim.x) {
        int mi = o / nCnt, n = o - mi * nCnt;
        const float* wr = &Wl[n * Kp];
        const float* ar = &Al[mi * Kp];
        float a0 = 0.f, a1 = 0.f, a2 = 0.f, a3 = 0.f;
        int k = 0;
        for (; k + 4 <= K; k += 4) {
            a0 += ar[k] * wr[k];
            a1 += ar[k + 1] * wr[k + 1];
            a2 += ar[k + 2] * wr[k + 2];
            a3 += ar[k + 3] * wr[k + 3];
        }
        for (; k < K; ++k) a0 += ar[k] * wr[k];
        float v = (a0 + a1) + (a2 + a3);
        if (bias) v += bias[nBase + n];
        C[(size_t)(m0 + mi) * ldc + nBase + n] = v;
    }
}

// ---------------------------------------------------------------------------
// K5: decoder greedy scan. One block per batch element.
// ---------------------------------------------------------------------------
__global__ __launch_bounds__(320) void dec_scan(
    const float* __restrict__ gi_lin,
    const float* __restrict__ whh, const float* __restrict__ bhh,
    const float* __restrict__ bih, const float* __restrict__ emb,
    const float* __restrict__ wih,
    const float* __restrict__ h2lw, const float* __restrict__ h2lb,
    const float* __restrict__ hT, float* __restrict__ out)
{
    __shared__ __align__(16) float h_s[H_];
    __shared__ float gh_s[G3];
    __shared__ float gi_s[G3];
    __shared__ float tc_s[NC_ * G3];
    __shared__ float hl_s[NC_ * H_];
    __shared__ float hlb_s[NC_];
    __shared__ float lg_s[NC_];
    __shared__ int prev_s;

    int b = blockIdx.x;
    int j = threadIdx.x;

    float4 wrow[25];
    float bh = 0.f;
    if (j < G3) {
        const float4* wr = (const float4*)(whh + (size_t)j * H_);
#pragma unroll
        for (int q = 0; q < 25; ++q) wrow[q] = wr[q];
        bh = bhh[j];
    }
    // label table: tc[c][jj] = bih[jj] + emb[c] . wih[jj][0:50]
    for (int idx = j; idx < NC_ * G3; idx += 320) {
        int c = idx / G3, jj = idx - c * G3;
        float acc = bih[jj];
        const float* er = emb + c * EMB_;
        const float* wr = wih + (size_t)jj * 150;
        for (int e = 0; e < EMB_; ++e) acc += er[e] * wr[e];
        tc_s[c * G3 + jj] = acc;
    }
    for (int idx = j; idx < NC_ * H_; idx += 320) hl_s[idx] = h2lw[idx];
    if (j < NC_) hlb_s[j] = h2lb[j];
    if (j < H_) h_s[j] = hT[b * H_ + j];
    if (j == 0) prev_s = 0;
    __syncthreads();

    for (int t = 0; t < S_; ++t) {
        int pv = prev_s;
        if (j < G3) {
            const float4* h4 = (const float4*)h_s;
            float a[4] = {0.f, 0.f, 0.f, 0.f};
#pragma unroll
            for (int q = 0; q < 25; ++q) a[q & 3] += dot4_(wrow[q], h4[q]);
            gh_s[j] = bh + (a[0] + a[1]) + (a[2] + a[3]);
            gi_s[j] = gi_lin[((size_t)t * B_ + b) * G3 + j] + tc_s[pv * G3 + j];
        }
        __syncthreads();
        if (j < H_) {
            float r = sigmoidf_(gi_s[j]          + gh_s[j]);
            float z = sigmoidf_(gi_s[H_ + j]     + gh_s[H_ + j]);
            float n = tanhf(    gi_s[2 * H_ + j] + r * gh_s[2 * H_ + j]);
            float hn = (1.f - z) * n + z * h_s[j];
            h_s[j] = hn;
        }
        __syncthreads();
        // logits: 10 classes x 8 partial lanes
        if (j < 80) {
            int c = j >> 3, part = j & 7;
            float acc = 0.f;
            for (int k = part; k < H_; k += 8) acc += hl_s[c * H_ + k] * h_s[k];
            for (int off = 1; off < 8; off <<= 1) acc += __shfl_xor(acc, off);
            if (part == 0) lg_s[c] = acc + hlb_s[c];
        }
        __syncthreads();
        if (j == 0) {
            float mxv = lg_s[0]; int am = 0;
            for (int c = 1; c < NC_; ++c) {
                float v = lg_s[c];
                if (v > mxv) { mxv = v; am = c; }
            }
            float se = 0.f;
            for (int c = 0; c < NC_; ++c) se += expf(lg_s[c] - mxv);
            float lse = mxv + logf(se);
            float* o = out + ((size_t)t * B_ + b) * NC_;
            for (int c = 0; c < NC_; ++c) o[c] = lg_s[c] - lse;
            prev_s = am;
        }
        __syncthreads();
    }
}

// ---------------------------------------------------------------------------
extern "C" void kernel_launch(void* const* d_in, const int* in_sizes, int n_in,
                              void* d_out, int out_size, void* d_ws, size_t ws_size,
                              hipStream_t stream)
{
    const float* hs   = (const float*)d_in[0];
    const int*   cb   = (const int*)  d_in[1];
    const float* fc5w = (const float*)d_in[2];
    const float* fc5b = (const float*)d_in[3];
    const float* ewif = (const float*)d_in[4];
    const float* ewhf = (const float*)d_in[5];
    const float* ebif = (const float*)d_in[6];
    const float* ebhf = (const float*)d_in[7];
    const float* ewib = (const float*)d_in[8];
    const float* ewhb = (const float*)d_in[9];
    const float* ebib = (const float*)d_in[10];
    const float* ebhb = (const float*)d_in[11];
    const float* emb  = (const float*)d_in[12];
    const float* l1w  = (const float*)d_in[13];
    const float* l1b  = (const float*)d_in[14];
    const float* dwih = (const float*)d_in[15];
    const float* dwhh = (const float*)d_in[16];
    const float* dbih = (const float*)d_in[17];
    const float* dbhh = (const float*)d_in[18];
    const float* h2lw = (const float*)d_in[19];
    const float* h2lb = (const float*)d_in[20];
    float* out = (float*)d_out;

    float* ws   = (float*)d_ws;
    float* doc  = ws;                  // [32*64, 768]   = 1572864
    float* gi   = doc  + 1572864;      // [2048, 600]    = 1228800
    float* out1 = gi   + 1228800;      // [2048, 200]    = 409600
    float* hT   = out1 + 409600;       // [64, 100]      = 6400
    float* lin  = hT   + 6400;         // [2048, 100]    = 204800
    float* gil  = lin  + 204800;       // [2048, 300]    = 614400

    pool_kernel<<<dim3(S_, B_), 256, 0, stream>>>(hs, cb, fc5w, fc5b, doc);
    gemm_enc<<<dim3(10, 32), 256, 0, stream>>>(doc, ewif, ewib, ebif, ebib, gi);
    enc_scan<<<128, 320, 0, stream>>>(gi, ewhf, ewhb, ebhf, ebhb, out1, hT);
    {   // lin = out1 @ l1w.T + l1b   [2048,200]x[100,200] -> [2048,100]
        size_t sh = (size_t)(64 + 8) * 201 * sizeof(float);
        small_gemm<<<dim3(2, 256), 256, sh, stream>>>(out1, 200, 200,
                                                      l1w, 200, 0, l1b,
                                                      lin, 100, 100, 8, 64);
    }
    {   // gil = lin @ dwih[:,50:150].T   [2048,100]x[300,100] -> [2048,300]
        size_t sh = (size_t)(150 + 8) * 101 * sizeof(float);
        small_gemm<<<dim3(2, 256), 256, sh, stream>>>(lin, 100, 100,
                                                      dwih, 150, 50, nullptr,
                                                      gil, 300, 300, 8, 150);
    }
    dec_scan<<<64, 320, 0, stream>>>(gil, dwhh, dbhh, dbih, emb, dwih,
                                     h2lw, h2lb, hT, out);
}

// Round 2
// 282.187 us; speedup vs baseline: 1.0727x; 1.0727x over previous
//
#include <hip/hip_runtime.h>
#include <hip/hip_bf16.h>
#include <math.h>

#define B_ 64
#define L_ 512
#define D_ 768
#define J_ 31
#define S_ 32
#define H_ 100
#define G3 300
#define NC_ 10
#define EMB_ 50

__device__ __forceinline__ float sigmoidf_(float x) { return 1.0f / (1.0f + expf(-x)); }
__device__ __forceinline__ float dot4_(float4 a, float4 b) {
    return a.x * b.x + a.y * b.y + a.z * b.z + a.w * b.w;
}

// ---------------------------------------------------------------------------
// K1: per-clause softmax-weighted pooling.  One block per (s, b).
// doc layout: [S][B][D]  (scan order)
// ---------------------------------------------------------------------------
#define TCAP 18
__global__ __launch_bounds__(256) void pool_kernel(
    const float* __restrict__ hs, const int* __restrict__ cb,
    const float* __restrict__ fc5w, const float* __restrict__ fc5b,
    float* __restrict__ doc)
{
    __shared__ __align__(16) float tile[TCAP * D_];
    __shared__ float sc_s[L_];
    __shared__ float red[8];

    int s = blockIdx.x, b = blockIdx.y;
    int start = (s == 0) ? 0 : cb[b * J_ + s - 1];
    int end   = (s == J_) ? L_ : cb[b * J_ + s];
    int nt = end - start;
    int tid = threadIdx.x;

    if (nt <= 0) {
        for (int d = tid; d < D_; d += 256) doc[((size_t)s * B_ + b) * D_ + d] = 0.f;
        return;
    }
    bool staged = (nt <= TCAP);
    const float* base = hs + ((size_t)b * L_ + start) * D_;

    if (staged) {
        const float4* b4 = (const float4*)base;
        float4* t4 = (float4*)tile;
        int n4 = nt * (D_ / 4);
        for (int i = tid; i < n4; i += 256) t4[i] = b4[i];
    }
    int lane = tid & 63, wv = tid >> 6;
    float fw[12];
#pragma unroll
    for (int i = 0; i < 12; ++i) fw[i] = fc5w[i * 64 + lane];
    __syncthreads();

    for (int t = wv; t < nt; t += 4) {
        const float* row = staged ? &tile[t * D_] : (base + (size_t)t * D_);
        float p = 0.f;
#pragma unroll
        for (int i = 0; i < 12; ++i) p += row[i * 64 + lane] * fw[i];
        for (int off = 32; off; off >>= 1) p += __shfl_xor(p, off);
        if (lane == 0) sc_s[t] = p + fc5b[0];
    }
    __syncthreads();

    float lm = -INFINITY;
    for (int i = tid; i < nt; i += 256) lm = fmaxf(lm, sc_s[i]);
    for (int off = 32; off; off >>= 1) lm = fmaxf(lm, __shfl_xor(lm, off));
    if (lane == 0) red[wv] = lm;
    __syncthreads();
    float mx = fmaxf(fmaxf(red[0], red[1]), fmaxf(red[2], red[3]));
    float ls = 0.f;
    for (int i = tid; i < nt; i += 256) {
        float e = expf(sc_s[i] - mx);
        sc_s[i] = e;
        ls += e;
    }
    for (int off = 32; off; off >>= 1) ls += __shfl_xor(ls, off);
    if (lane == 0) red[4 + wv] = ls;
    __syncthreads();
    float inv = 1.f / (red[4] + red[5] + red[6] + red[7]);

    float acc0 = 0.f, acc1 = 0.f, acc2 = 0.f;
    for (int t = 0; t < nt; ++t) {
        float w = sc_s[t] * inv;
        const float* row = staged ? &tile[t * D_] : (base + (size_t)t * D_);
        acc0 += w * row[tid];
        acc1 += w * row[256 + tid];
        acc2 += w * row[512 + tid];
    }
    float* o = doc + ((size_t)s * B_ + b) * D_;
    o[tid] = acc0; o[256 + tid] = acc1; o[512 + tid] = acc2;
}

// ---------------------------------------------------------------------------
// K2: gi = doc @ [Wf;Wb].T + [bf;bb]   M=2048, N=600, K=768  (64x64 tiles)
// ---------------------------------------------------------------------------
__global__ __launch_bounds__(256) void gemm_enc(
    const float* __restrict__ A,
    const float* __restrict__ Wf, const float* __restrict__ Wb,
    const float* __restrict__ bf_, const float* __restrict__ bb_,
    float* __restrict__ C)
{
    __shared__ __align__(16) float As[16][68];
    __shared__ __align__(16) float Ws[16][68];
    int n0 = blockIdx.x * 64, m0 = blockIdx.y * 64;
    int tid = threadIdx.x;
    int tx = tid & 15, ty = tid >> 4;
    int lr = tid >> 2, lk4 = tid & 3;
    float acc[4][4] = {};

    for (int kk = 0; kk < D_; kk += 16) {
        float4 av = *(const float4*)(A + ((size_t)(m0 + lr)) * D_ + kk + lk4 * 4);
        As[lk4 * 4 + 0][lr] = av.x; As[lk4 * 4 + 1][lr] = av.y;
        As[lk4 * 4 + 2][lr] = av.z; As[lk4 * 4 + 3][lr] = av.w;
        int n = n0 + lr;
        float4 wvv = make_float4(0.f, 0.f, 0.f, 0.f);
        if (n < G3)      wvv = *(const float4*)(Wf + (size_t)n * D_ + kk + lk4 * 4);
        else if (n < 600) wvv = *(const float4*)(Wb + (size_t)(n - G3) * D_ + kk + lk4 * 4);
        Ws[lk4 * 4 + 0][lr] = wvv.x; Ws[lk4 * 4 + 1][lr] = wvv.y;
        Ws[lk4 * 4 + 2][lr] = wvv.z; Ws[lk4 * 4 + 3][lr] = wvv.w;
        __syncthreads();
#pragma unroll
        for (int k = 0; k < 16; ++k) {
            float4 a4 = *(const float4*)&As[k][ty * 4];
            float4 w4 = *(const float4*)&Ws[k][tx * 4];
            float ai[4] = {a4.x, a4.y, a4.z, a4.w};
            float wj[4] = {w4.x, w4.y, w4.z, w4.w};
#pragma unroll
            for (int i = 0; i < 4; ++i)
#pragma unroll
                for (int j = 0; j < 4; ++j) acc[i][j] += ai[i] * wj[j];
        }
        __syncthreads();
    }
#pragma unroll
    for (int j = 0; j < 4; ++j) {
        int n = n0 + tx * 4 + j;
        if (n >= 600) continue;
        float bias = (n < G3) ? bf_[n] : bb_[n - G3];
#pragma unroll
        for (int i = 0; i < 4; ++i) {
            int m = m0 + ty * 4 + i;
            C[(size_t)m * 600 + n] = acc[i][j] + bias;
        }
    }
}

// ---------------------------------------------------------------------------
// K3: encoder scans.  128 blocks: bid<64 fwd batch, bid>=64 bwd batch.
// 640 threads: Whh row j split across thread pair (j,part) -> 13 float4 each
// (no spill).  gi slab for this (b,dir) staged in LDS.
// ---------------------------------------------------------------------------
#define ENCT 640
__global__ __launch_bounds__(ENCT) void enc_scan(
    const float* __restrict__ gi,
    const float* __restrict__ whh_f, const float* __restrict__ whh_b,
    const float* __restrict__ bhh_f, const float* __restrict__ bhh_b,
    float* __restrict__ out1, float* __restrict__ hT)
{
    __shared__ float gis[S_ * G3];           // 38400 B
    __shared__ __align__(16) float h_s[H_];
    __shared__ float gh_s[G3];

    int bid = blockIdx.x;
    int b = bid & 63;
    bool bwd = (bid >= 64);
    const float* whh = bwd ? whh_b : whh_f;
    const float* bhh = bwd ? bhh_b : bhh_f;
    int tid = threadIdx.x;
    int j = tid >> 1, part = tid & 1;

    // stage gi for this (b, dir): [S][G3]
    for (int idx = tid; idx < S_ * G3; idx += ENCT) {
        int t = idx / G3, jj = idx - t * G3;
        gis[idx] = gi[((size_t)t * B_ + b) * 600 + (bwd ? G3 : 0) + jj];
    }

    float4 wr[13];
    float bh = 0.f;
    if (tid < 600) {
        const float4* wbase = (const float4*)(whh + (size_t)j * H_) + part * 12;
#pragma unroll
        for (int q = 0; q < 13; ++q) wr[q] = wbase[q];
        if (!part) wr[12] = make_float4(0.f, 0.f, 0.f, 0.f);
        bh = bhh[j];
    }
    if (tid < H_) h_s[tid] = 0.f;
    __syncthreads();

    for (int step = 0; step < S_; ++step) {
        int t = bwd ? (S_ - 1 - step) : step;
        if (tid < 600) {
            const float4* h4 = ((const float4*)h_s) + part * 12;
            float a[4] = {0.f, 0.f, 0.f, 0.f};
#pragma unroll
            for (int q = 0; q < 13; ++q) a[q & 3] += dot4_(wr[q], h4[q]);
            float sdot = (a[0] + a[1]) + (a[2] + a[3]);
            sdot += __shfl_xor(sdot, 1);
            if (!part) gh_s[j] = sdot + bh;
        }
        __syncthreads();
        if (tid < H_) {
            const float* g = gis + t * G3;
            float r = sigmoidf_(g[tid]          + gh_s[tid]);
            float z = sigmoidf_(g[H_ + tid]     + gh_s[H_ + tid]);
            float n = tanhf(    g[2 * H_ + tid] + r * gh_s[2 * H_ + tid]);
            float hn = (1.f - z) * n + z * h_s[tid];
            h_s[tid] = hn;
            out1[((size_t)t * B_ + b) * 200 + (bwd ? H_ : 0) + tid] = hn;
        }
        __syncthreads();
    }
    if (!bwd && tid < H_) hT[b * H_ + tid] = h_s[tid];
}

// ---------------------------------------------------------------------------
// K4: generic small NT GEMM: C[m][n] = sum_k A[m][k]*W[n][woff+k] (+bias[n])
// ---------------------------------------------------------------------------
__global__ void small_gemm(
    const float* __restrict__ A, int lda, int K,
    const float* __restrict__ W, int wstride, int woff,
    const float* __restrict__ bias,
    float* __restrict__ C, int N, int ldc,
    int BM, int nChunk)
{
    extern __shared__ float sm[];
    int Kp = K + 1;
    float* Wl = sm;
    float* Al = sm + (size_t)nChunk * Kp;
    int nBase = blockIdx.x * nChunk;
    int nCnt = min(nChunk, N - nBase);
    int m0 = blockIdx.y * BM;

    for (int i = threadIdx.x; i < nCnt * K; i += blockDim.x) {
        int n = i / K, k = i - n * K;
        Wl[n * Kp + k] = W[(size_t)(nBase + n) * wstride + woff + k];
    }
    for (int i = threadIdx.x; i < BM * K; i += blockDim.x) {
        int mi = i / K, k = i - mi * K;
        Al[mi * Kp + k] = A[(size_t)(m0 + mi) * lda + k];
    }
    __syncthreads();

    for (int o = threadIdx.x; o < BM * nCnt; o += blockDim.x) {
        int mi = o / nCnt, n = o - mi * nCnt;
        const float* wr = &Wl[n * Kp];
        const float* ar = &Al[mi * Kp];
        float a0 = 0.f, a1 = 0.f, a2 = 0.f, a3 = 0.f;
        int k = 0;
        for (; k + 4 <= K; k += 4) {
            a0 += ar[k] * wr[k];
            a1 += ar[k + 1] * wr[k + 1];
            a2 += ar[k + 2] * wr[k + 2];
            a3 += ar[k + 3] * wr[k + 3];
        }
        for (; k < K; ++k) a0 += ar[k] * wr[k];
        float v = (a0 + a1) + (a2 + a3);
        if (bias) v += bias[nBase + n];
        C[(size_t)(m0 + mi) * ldc + nBase + n] = v;
    }
}

// ---------------------------------------------------------------------------
// K5: decoder greedy scan. One block per batch element, 640 threads,
// Whh split across thread pairs (no spill), gi_lin staged in LDS.
// ---------------------------------------------------------------------------
__global__ __launch_bounds__(ENCT) void dec_scan(
    const float* __restrict__ gi_lin,
    const float* __restrict__ whh, const float* __restrict__ bhh,
    const float* __restrict__ bih, const float* __restrict__ emb,
    const float* __restrict__ wih,
    const float* __restrict__ h2lw, const float* __restrict__ h2lb,
    const float* __restrict__ hT, float* __restrict__ out)
{
    __shared__ float gils[S_ * G3];          // 38400 B
    __shared__ float tc_s[NC_ * G3];         // 12000 B
    __shared__ float hl_s[NC_ * H_];         // 4000 B
    __shared__ __align__(16) float h_s[H_];
    __shared__ float gh_s[G3];
    __shared__ float hlb_s[NC_];
    __shared__ float lg_s[NC_];
    __shared__ int prev_s;

    int b = blockIdx.x;
    int tid = threadIdx.x;
    int j = tid >> 1, part = tid & 1;

    for (int idx = tid; idx < S_ * G3; idx += ENCT) {
        int t = idx / G3, jj = idx - t * G3;
        gils[idx] = gi_lin[((size_t)t * B_ + b) * G3 + jj];
    }
    // label table: tc[c][jj] = bih[jj] + emb[c] . wih[jj][0:50]
    for (int idx = tid; idx < NC_ * G3; idx += ENCT) {
        int c = idx / G3, jj = idx - c * G3;
        float acc = bih[jj];
        const float* er = emb + c * EMB_;
        const float* wrp = wih + (size_t)jj * 150;
        for (int e = 0; e < EMB_; ++e) acc += er[e] * wrp[e];
        tc_s[c * G3 + jj] = acc;
    }
    for (int idx = tid; idx < NC_ * H_; idx += ENCT) hl_s[idx] = h2lw[idx];
    if (tid < NC_) hlb_s[tid] = h2lb[tid];
    if (tid < H_) h_s[tid] = hT[b * H_ + tid];
    if (tid == 0) prev_s = 0;

    float4 wr[13];
    float bh = 0.f;
    if (tid < 600) {
        const float4* wbase = (const float4*)(whh + (size_t)j * H_) + part * 12;
#pragma unroll
        for (int q = 0; q < 13; ++q) wr[q] = wbase[q];
        if (!part) wr[12] = make_float4(0.f, 0.f, 0.f, 0.f);
        bh = bhh[j];
    }
    __syncthreads();

    for (int t = 0; t < S_; ++t) {
        int pv = prev_s;
        if (tid < 600) {
            const float4* h4 = ((const float4*)h_s) + part * 12;
            float a[4] = {0.f, 0.f, 0.f, 0.f};
#pragma unroll
            for (int q = 0; q < 13; ++q) a[q & 3] += dot4_(wr[q], h4[q]);
            float sdot = (a[0] + a[1]) + (a[2] + a[3]);
            sdot += __shfl_xor(sdot, 1);
            if (!part) gh_s[j] = sdot + bh;
        }
        __syncthreads();
        if (tid < H_) {
            const float* g = gils + t * G3;
            const float* tc = tc_s + pv * G3;
            float gr = g[tid]          + tc[tid];
            float gz = g[H_ + tid]     + tc[H_ + tid];
            float gn = g[2 * H_ + tid] + tc[2 * H_ + tid];
            float r = sigmoidf_(gr + gh_s[tid]);
            float z = sigmoidf_(gz + gh_s[H_ + tid]);
            float n = tanhf(    gn + r * gh_s[2 * H_ + tid]);
            float hn = (1.f - z) * n + z * h_s[tid];
            h_s[tid] = hn;
        }
        __syncthreads();
        if (tid < 80) {
            int c = tid >> 3, pt = tid & 7;
            float acc = 0.f;
            for (int k = pt; k < H_; k += 8) acc += hl_s[c * H_ + k] * h_s[k];
            for (int off = 1; off < 8; off <<= 1) acc += __shfl_xor(acc, off);
            if (pt == 0) lg_s[c] = acc + hlb_s[c];
        }
        __syncthreads();
        if (tid == 0) {
            float mxv = lg_s[0]; int am = 0;
            for (int c = 1; c < NC_; ++c) {
                float v = lg_s[c];
                if (v > mxv) { mxv = v; am = c; }
            }
            float se = 0.f;
            for (int c = 0; c < NC_; ++c) se += expf(lg_s[c] - mxv);
            float lse = mxv + logf(se);
            float* o = out + ((size_t)t * B_ + b) * NC_;
            for (int c = 0; c < NC_; ++c) o[c] = lg_s[c] - lse;
            prev_s = am;
        }
        __syncthreads();
    }
}

// ---------------------------------------------------------------------------
extern "C" void kernel_launch(void* const* d_in, const int* in_sizes, int n_in,
                              void* d_out, int out_size, void* d_ws, size_t ws_size,
                              hipStream_t stream)
{
    const float* hs   = (const float*)d_in[0];
    const int*   cb   = (const int*)  d_in[1];
    const float* fc5w = (const float*)d_in[2];
    const float* fc5b = (const float*)d_in[3];
    const float* ewif = (const float*)d_in[4];
    const float* ewhf = (const float*)d_in[5];
    const float* ebif = (const float*)d_in[6];
    const float* ebhf = (const float*)d_in[7];
    const float* ewib = (const float*)d_in[8];
    const float* ewhb = (const float*)d_in[9];
    const float* ebib = (const float*)d_in[10];
    const float* ebhb = (const float*)d_in[11];
    const float* emb  = (const float*)d_in[12];
    const float* l1w  = (const float*)d_in[13];
    const float* l1b  = (const float*)d_in[14];
    const float* dwih = (const float*)d_in[15];
    const float* dwhh = (const float*)d_in[16];
    const float* dbih = (const float*)d_in[17];
    const float* dbhh = (const float*)d_in[18];
    const float* h2lw = (const float*)d_in[19];
    const float* h2lb = (const float*)d_in[20];
    float* out = (float*)d_out;

    float* ws   = (float*)d_ws;
    float* doc  = ws;                  // [32*64, 768]   = 1572864
    float* gi   = doc  + 1572864;      // [2048, 600]    = 1228800
    float* out1 = gi   + 1228800;      // [2048, 200]    = 409600
    float* hT   = out1 + 409600;       // [64, 100]      = 6400
    float* lin  = hT   + 6400;         // [2048, 100]    = 204800
    float* gil  = lin  + 204800;       // [2048, 300]    = 614400

    pool_kernel<<<dim3(S_, B_), 256, 0, stream>>>(hs, cb, fc5w, fc5b, doc);
    gemm_enc<<<dim3(10, 32), 256, 0, stream>>>(doc, ewif, ewib, ebif, ebib, gi);
    enc_scan<<<128, ENCT, 0, stream>>>(gi, ewhf, ewhb, ebhf, ebhb, out1, hT);
    {   // lin = out1 @ l1w.T + l1b   [2048,200]x[100,200] -> [2048,100]
        size_t sh = (size_t)(64 + 8) * 201 * sizeof(float);
        small_gemm<<<dim3(2, 256), 256, sh, stream>>>(out1, 200, 200,
                                                      l1w, 200, 0, l1b,
                                                      lin, 100, 100, 8, 64);
    }
    {   // gil = lin @ dwih[:,50:150].T   [2048,100]x[300,100] -> [2048,300]
        size_t sh = (size_t)(150 + 8) * 101 * sizeof(float);
        small_gemm<<<dim3(2, 256), 256, sh, stream>>>(lin, 100, 100,
                                                      dwih, 150, 50, nullptr,
                                                      gil, 300, 300, 8, 150);
    }
    dec_scan<<<64, ENCT, 0, stream>>>(gil, dwhh, dbhh, dbih, emb, dwih,
                                      h2lw, h2lb, hT, out);
}